// Round 6
// baseline (131.241 us; speedup 1.0000x reference)
//
#include <hip/hip_runtime.h>

#define NPTS 65536
#define NB_SHIFT 16   // log2(NPTS)
#define KNBR 16
#define HID 64
#define PPB 128       // points per block in main kernel (2 threads per point)

// native clang vector types — required by __builtin_nontemporal_{load,store}
typedef int   i32x4 __attribute__((ext_vector_type(4)));
typedef float f32x4 __attribute__((ext_vector_type(4)));

// address-space-qualified aliases for __builtin_amdgcn_global_load_lds
typedef __attribute__((address_space(1))) const void as1_cv;
typedef __attribute__((address_space(3))) void       as3_v;

// 16B LDS-DMA gather: per-lane GLOBAL address, wave-uniform LDS base;
// HW writes lane i's 16B at ldsbase + i*16.
__device__ __forceinline__ void gather_lds16(const void* g, void* l) {
    __builtin_amdgcn_global_load_lds((as1_cv*)g, (as3_v*)l, 16, 0, 0);
}

// ---------------- pre-pass: pos (B,3,N) -> xyzt (B,N) float4 ----------------
// NT store: table lands clean in L3; reader XCDs replicate it into local L2.
__global__ __launch_bounds__(256) void xyzt_kernel(const float* __restrict__ pos,
                                                   f32x4* __restrict__ xyzt) {
    const int tid = threadIdx.x;
    const int blk = ((int)blockIdx.x & 7) * 128 + ((int)blockIdx.x >> 3);
    const int g = blk * 256 + tid;
    const int b = g >> NB_SHIFT;
    const int n = g & (NPTS - 1);
    const float* p = pos + (size_t)b * 3 * NPTS;
    f32x4 v;
    v.x = __builtin_nontemporal_load(p + n);            // pos streamed once
    v.y = __builtin_nontemporal_load(p + n + NPTS);
    v.z = __builtin_nontemporal_load(p + n + 2 * NPTS);
    v.w = 0.f;
    __builtin_nontemporal_store(v, xyzt + ((size_t)b << NB_SHIFT) + n);
}

// ---------------- main kernel ----------------
// Pair-split (2 threads/point). Gathers now go through the LDS-DMA path
// (global_load_lds with per-lane global address) to test whether it has a
// deeper outstanding-request pool than the vector-return path (which is
// pinned at ~0.17 req/cyc/CU = MSHR_cap/L2_latency across 5 variants).
template <int USE_T>
__global__ __launch_bounds__(256) void point_embed_kernel(
    const float*  __restrict__ pos,
    const float4* __restrict__ xyzt,
    const int*    __restrict__ idx,
    const float*  __restrict__ dist,
    const float*  __restrict__ W,
    const float*  __restrict__ bias,
    float*        __restrict__ out) {
    __shared__ float feat[10][PPB];
    __shared__ f32x4 gbuf[4][8][64];   // wave, slot, lane : 32 KB
    const int tid = threadIdx.x;
    const int wv  = tid >> 6;          // wave id 0..3
    const int ln  = tid & 63;          // lane id

    // XCD-aware swizzle: contiguous block ranges per XCD -> per-XCD gather
    // working set = 1 batch table (1 MB), L2-resident.
    const int blk = ((int)blockIdx.x & 7) * 256 + ((int)blockIdx.x >> 3);
    const int p = tid >> 1;                           // 0..127 point-in-block
    const int h = tid & 1;                            // which half of K
    const int g = blk * PPB + p;                      // global point id
    const int b = g >> NB_SHIFT;
    const int n = g & (NPTS - 1);

    // --- W slice for phase 2: this thread owns hidden cols 4*hq .. 4*hq+3 ---
    const int hq = tid & 15;
    float4 Wv[10];
#pragma unroll
    for (int c = 0; c < 10; ++c)
        Wv[c] = ((const float4*)(W + c * HID))[hq];
    const float4 bv = ((const float4*)bias)[hq];

    // --- phase 1: per-point feature (10 floats), split across the pair ---
    const i32x4* iv = (const i32x4*)idx + (size_t)g * 4 + h * 2;
    i32x4 i0 = __builtin_nontemporal_load(iv + 0);
    i32x4 i1 = __builtin_nontemporal_load(iv + 1);
    const f32x4* dv = (const f32x4*)dist + (size_t)g * 4 + h * 2;
    f32x4 d0 = __builtin_nontemporal_load(dv + 0);
    f32x4 d1 = __builtin_nontemporal_load(dv + 1);
    float maxd = fmaxf(fmaxf(fmaxf(d0.x, d0.y), fmaxf(d0.z, d0.w)),
                       fmaxf(fmaxf(d1.x, d1.y), fmaxf(d1.z, d1.w)));

    float cx, cy, cz;
    float mxx = -INFINITY, mxy = -INFINITY, mxz = -INFINITY;
    float mnx = INFINITY, mny = INFINITY, mnz = INFINITY;

    if (USE_T) {
        const f32x4* xb = (const f32x4*)(xyzt + ((size_t)b << NB_SHIFT));
        // center load: coalesced across the wave -> cached path is fine
        float4 c = xyzt[((size_t)b << NB_SHIFT) + n];
        cx = c.x; cy = c.y; cz = c.z;

        // 8 LDS-DMA gathers: per-lane global addr, wave-uniform LDS slot base.
        gather_lds16(xb + i0.x, &gbuf[wv][0][0]);
        gather_lds16(xb + i0.y, &gbuf[wv][1][0]);
        gather_lds16(xb + i0.z, &gbuf[wv][2][0]);
        gather_lds16(xb + i0.w, &gbuf[wv][3][0]);
        gather_lds16(xb + i1.x, &gbuf[wv][4][0]);
        gather_lds16(xb + i1.y, &gbuf[wv][5][0]);
        gather_lds16(xb + i1.z, &gbuf[wv][6][0]);
        gather_lds16(xb + i1.w, &gbuf[wv][7][0]);
        asm volatile("s_waitcnt vmcnt(0)" ::: "memory");   // DMA -> LDS complete
        __builtin_amdgcn_sched_barrier(0);  // rule-18: keep LDS reads below wait

#define RED(S)                                    \
    {                                             \
        f32x4 q = gbuf[wv][(S)][ln];              \
        mxx = fmaxf(mxx, q.x);                    \
        mxy = fmaxf(mxy, q.y);                    \
        mxz = fmaxf(mxz, q.z);                    \
        mnx = fminf(mnx, q.x);                    \
        mny = fminf(mny, q.y);                    \
        mnz = fminf(mnz, q.z);                    \
    }
        RED(0) RED(1) RED(2) RED(3) RED(4) RED(5) RED(6) RED(7)
#undef RED
    } else {
        const float* px = pos + (size_t)b * 3 * NPTS;
        cx = px[n]; cy = px[n + NPTS]; cz = px[n + 2 * NPTS];
#define GATH(J)                                   \
    {                                             \
        float qx = px[(J)];                       \
        float qy = px[(J) + NPTS];                \
        float qz = px[(J) + 2 * NPTS];            \
        mxx = fmaxf(mxx, qx);                     \
        mxy = fmaxf(mxy, qy);                     \
        mxz = fmaxf(mxz, qz);                     \
        mnx = fminf(mnx, qx);                     \
        mny = fminf(mny, qy);                     \
        mnz = fminf(mnz, qz);                     \
    }
        GATH(i0.x) GATH(i0.y) GATH(i0.z) GATH(i0.w)
        GATH(i1.x) GATH(i1.y) GATH(i1.z) GATH(i1.w)
#undef GATH
    }

    // --- merge the pair (lanes 2p and 2p+1 are in the same wave) ---
    mxx = fmaxf(mxx, __shfl_xor(mxx, 1));
    mxy = fmaxf(mxy, __shfl_xor(mxy, 1));
    mxz = fmaxf(mxz, __shfl_xor(mxz, 1));
    mnx = fminf(mnx, __shfl_xor(mnx, 1));
    mny = fminf(mny, __shfl_xor(mny, 1));
    mnz = fminf(mnz, __shfl_xor(mnz, 1));
    maxd = fmaxf(maxd, __shfl_xor(maxd, 1));

    if (h == 0) {
        feat[0][p] = cx;
        feat[1][p] = cy;
        feat[2][p] = cz;
        feat[3][p] = mxx;
        feat[4][p] = mxy;
        feat[5][p] = mxz;
        feat[6][p] = cx - mnx;
        feat[7][p] = cy - mny;
        feat[8][p] = cz - mnz;
        feat[9][p] = maxd;
    }
    __syncthreads();

    // --- phase 2: 128 points x 64 hidden, coalesced nontemporal float4 stores ---
    const int prow = tid >> 4;                       // 0..15
    const size_t outbase = (size_t)blk * PPB * HID;
#pragma unroll
    for (int i = 0; i < 8; ++i) {
        const int pp = i * 16 + prow;                // 0..127
        float4 acc = bv;
#pragma unroll
        for (int c = 0; c < 10; ++c) {
            const float fv = feat[c][pp];
            acc.x += fv * Wv[c].x;
            acc.y += fv * Wv[c].y;
            acc.z += fv * Wv[c].z;
            acc.w += fv * Wv[c].w;
        }
        f32x4 av;
        av.x = fmaxf(acc.x, 0.f);
        av.y = fmaxf(acc.y, 0.f);
        av.z = fmaxf(acc.z, 0.f);
        av.w = fmaxf(acc.w, 0.f);
        // out written once, never read back: don't write-allocate 67 MB in L2
        __builtin_nontemporal_store(av,
            (f32x4*)(out + outbase + (size_t)pp * HID) + hq);
    }
}

extern "C" void kernel_launch(void* const* d_in, const int* in_sizes, int n_in,
                              void* d_out, int out_size, void* d_ws, size_t ws_size,
                              hipStream_t stream) {
    const float* pos  = (const float*)d_in[0];
    const int*   idx  = (const int*)d_in[1];
    const float* dist = (const float*)d_in[2];
    const float* W    = (const float*)d_in[3];
    const float* bias = (const float*)d_in[4];
    float* out = (float*)d_out;

    const int total = in_sizes[0] / 3;       // B*N = 262144
    const size_t need = (size_t)total * sizeof(float4);  // 16 MB

    if (ws_size >= need) {
        xyzt_kernel<<<total / 256, 256, 0, stream>>>(pos, (f32x4*)d_ws);
        point_embed_kernel<1><<<total / PPB, 256, 0, stream>>>(
            pos, (const float4*)d_ws, idx, dist, W, bias, out);
    } else {
        point_embed_kernel<0><<<total / PPB, 256, 0, stream>>>(
            pos, nullptr, idx, dist, W, bias, out);
    }
}